// Round 7
// baseline (931.561 us; speedup 1.0000x reference)
//
#include <hip/hip_runtime.h>
#include <hip/hip_bf16.h>
#include <math.h>

constexpr int L_LEVELS = 16;
constexpr unsigned TABLE_SIZE = 1u << 19;
constexpr unsigned TMASK = TABLE_SIZE - 1u;
constexpr int N_PTS = 1048576;

typedef __bf16 bf16x8 __attribute__((ext_vector_type(8)));
typedef float f32x4 __attribute__((ext_vector_type(4)));

struct EncP {
    float scale[L_LEVELS];
    unsigned res[L_LEVELS];
    unsigned fine[L_LEVELS];   // 1 => working set >256KB: bypass L1 (nt)
};

struct alignas(8) f4_8 { float x, y, z, w; };

// ---------------------------------------------------------------------------
// Kernel 1: grid encode, one (point, level) per thread. R4/R5-proven structure
// (branch-per-pair, serial consumption). NEW: fine levels (working set >256KB,
// ~0% L1 hit) gather with `nt` (L1-bypass) dwordx4 -> tests whether the
// ~0.2 req/cy/CU wall is the L1 miss path (MSHR) or L2 service rate.
// Level-phased XCD-pinned blockIdx decode (proven: FETCH 3.1GB -> 0.33GB).
// ---------------------------------------------------------------------------
__global__ __launch_bounds__(256) void encode_kernel(
    const float* __restrict__ x,
    const float* __restrict__ table,
    unsigned* __restrict__ wsu,
    EncP p)
{
    const unsigned bid = blockIdx.x;
    const unsigned level = (bid & 7u) + 8u * (bid >> 15);
    const unsigned pblk  = (bid >> 3) & 4095u;
    const unsigned n = pblk * 256u + threadIdx.x;

    const float x0 = x[n * 3 + 0];
    const float x1 = x[n * 3 + 1];
    const float x2 = x[n * 3 + 2];

    const float s = p.scale[level];
    const unsigned r = p.res[level];
    const unsigned r2 = r * r;                   // uint32 wrap == int32 wrap bits

    float px = x0 * s + 0.5f;
    float py = x1 * s + 0.5f;
    float pz = x2 * s + 0.5f;
    float gx = floorf(px), gy = floorf(py), gz = floorf(pz);
    float fx = px - gx, fy = py - gy, fz = pz - gz;
    unsigned base = (unsigned)(int)gx + (unsigned)(int)gy * r + (unsigned)(int)gz * r2;

    const float* tl = table + (size_t)level * (size_t)TABLE_SIZE * 2u;
    const float fx1 = 1.f - fx, fy1 = 1.f - fy, fz1 = 1.f - fz;
    const float w00 = fy1 * fz1, w01 = fy1 * fz, w10 = fy * fz1, w11 = fy * fz;
    float a0 = 0.f, a1 = 0.f;

#define PAIR_TAIL(WYZ)                                    \
    {                                                     \
        const float m0 = fmaf(fx, f10, fx1 * f00);        \
        const float m1 = fmaf(fx, f11, fx1 * f01);        \
        a0 = fmaf((WYZ), m0, a0);                         \
        a1 = fmaf((WYZ), m1, a1);                         \
    }

#define PAIR_SLOW(idx0)                                             \
    {                                                               \
        const float2 aa = *(const float2*)(tl + 2u * (idx0));       \
        const float2 bb = *(const float2*)(tl + 2u * (((idx0) + 1u) & TMASK)); \
        f00 = aa.x; f01 = aa.y; f10 = bb.x; f11 = bb.y;             \
    }

#define PAIR_C(LIN, WYZ)                                            \
    {                                                               \
        const unsigned idx0 = (LIN) & TMASK;                        \
        float f00, f01, f10, f11;                                   \
        if (__builtin_expect(idx0 != TMASK, 1)) {                   \
            const f4_8 f = *(const f4_8*)(tl + 2u * idx0);          \
            f00 = f.x; f01 = f.y; f10 = f.z; f11 = f.w;             \
        } else PAIR_SLOW(idx0)                                      \
        PAIR_TAIL(WYZ)                                              \
    }

#define PAIR_NT(LIN, WYZ)                                           \
    {                                                               \
        const unsigned idx0 = (LIN) & TMASK;                        \
        float f00, f01, f10, f11;                                   \
        if (__builtin_expect(idx0 != TMASK, 1)) {                   \
            const float* ap = tl + 2u * idx0;                       \
            f32x4 fv;                                               \
            asm volatile("global_load_dwordx4 %0, %1, off nt\n\t"   \
                         "s_waitcnt vmcnt(0)"                       \
                         : "=&v"(fv) : "v"(ap));                    \
            f00 = fv.x; f01 = fv.y; f10 = fv.z; f11 = fv.w;         \
        } else PAIR_SLOW(idx0)                                      \
        PAIR_TAIL(WYZ)                                              \
    }

    if (p.fine[level]) {
        PAIR_NT(base,           w00)   // dy=0,dz=0
        PAIR_NT(base + r2,      w01)   // dy=0,dz=1
        PAIR_NT(base + r,       w10)   // dy=1,dz=0
        PAIR_NT(base + r + r2,  w11)   // dy=1,dz=1
    } else {
        PAIR_C(base,           w00)
        PAIR_C(base + r2,      w01)
        PAIR_C(base + r,       w10)
        PAIR_C(base + r + r2,  w11)
    }
#undef PAIR_C
#undef PAIR_NT
#undef PAIR_SLOW
#undef PAIR_TAIL

    __hip_bfloat162 hv = __float22bfloat162_rn(make_float2(a0, a1));
    unsigned u;
    __builtin_memcpy(&u, &hv, 4);
    wsu[(size_t)level * N_PTS + n] = u;   // coalesced u32
}

// ---------------------------------------------------------------------------
// Kernel 2: MFMA MLP 32->64->64->32 (bf16 in, fp32 accum). Proven R5: ~29us.
// ---------------------------------------------------------------------------
__global__ __launch_bounds__(256) void mlp_mfma_kernel(
    const unsigned* __restrict__ wsu,
    const float* __restrict__ W1,
    const float* __restrict__ W2,
    const float* __restrict__ W3,
    float* __restrict__ out)
{
    __shared__ __align__(16) unsigned short xin[64 * 40];   // [pt][feat] pad 40
    __shared__ __align__(16) unsigned short H1[64 * 72];    // [pt][feat] pad 72
    __shared__ __align__(16) unsigned short H2[64 * 72];

    const int tid = threadIdx.x;
    const int l  = tid & 63;
    const int w  = tid >> 6;
    const int lr = l & 15;    // frag row (A) / col (B,D)
    const int lg = l >> 4;    // k-group

    bf16x8 b1[4], b2[4][2], b3[2][2];
#pragma unroll
    for (int cb = 0; cb < 4; ++cb)
#pragma unroll
        for (int e = 0; e < 8; ++e)
            b1[cb][e] = (__bf16)W1[(lg * 8 + e) * 64 + cb * 16 + lr];
#pragma unroll
    for (int cb = 0; cb < 4; ++cb)
#pragma unroll
        for (int kh = 0; kh < 2; ++kh)
#pragma unroll
            for (int e = 0; e < 8; ++e)
                b2[cb][kh][e] = (__bf16)W2[(kh * 32 + lg * 8 + e) * 64 + cb * 16 + lr];
#pragma unroll
    for (int cb = 0; cb < 2; ++cb)
#pragma unroll
        for (int kh = 0; kh < 2; ++kh)
#pragma unroll
            for (int e = 0; e < 8; ++e)
                b3[cb][kh][e] = (__bf16)W3[(kh * 32 + lg * 8 + e) * 32 + cb * 16 + lr];

    constexpr int ITERS = 8;
    const int tile0 = blockIdx.x * ITERS;
    const f32x4 z = {0.f, 0.f, 0.f, 0.f};

    for (int it = 0; it < ITERS; ++it) {
        const int p0 = (tile0 + it) * 64;

        {
            const int i  = tid & 63;
            const int lb = tid >> 6;
#pragma unroll
            for (int ps = 0; ps < 4; ++ps) {
                const int lev = ps * 4 + lb;
                const unsigned v = wsu[(size_t)lev * N_PTS + p0 + i];
                *(unsigned*)&xin[i * 40 + 2 * lev] = v;
            }
        }
        __syncthreads();

        const int row = w * 16 + lr;

        const bf16x8 a1 = *(const bf16x8*)&xin[row * 40 + lg * 8];
        f32x4 d1[4];
#pragma unroll
        for (int cb = 0; cb < 4; ++cb)
            d1[cb] = __builtin_amdgcn_mfma_f32_16x16x32_bf16(a1, b1[cb], z, 0, 0, 0);
#pragma unroll
        for (int cb = 0; cb < 4; ++cb)
#pragma unroll
            for (int reg = 0; reg < 4; ++reg) {
                const __bf16 hv = (__bf16)fmaxf(d1[cb][reg], 0.f);
                unsigned short bits;
                __builtin_memcpy(&bits, &hv, 2);
                H1[(w * 16 + lg * 4 + reg) * 72 + cb * 16 + lr] = bits;
            }

        const bf16x8 a2_0 = *(const bf16x8*)&H1[row * 72 + lg * 8];
        const bf16x8 a2_1 = *(const bf16x8*)&H1[row * 72 + 32 + lg * 8];
        f32x4 d2[4];
#pragma unroll
        for (int cb = 0; cb < 4; ++cb) {
            f32x4 t = __builtin_amdgcn_mfma_f32_16x16x32_bf16(a2_0, b2[cb][0], z, 0, 0, 0);
            d2[cb]  = __builtin_amdgcn_mfma_f32_16x16x32_bf16(a2_1, b2[cb][1], t, 0, 0, 0);
        }
#pragma unroll
        for (int cb = 0; cb < 4; ++cb)
#pragma unroll
            for (int reg = 0; reg < 4; ++reg) {
                const __bf16 hv = (__bf16)fmaxf(d2[cb][reg], 0.f);
                unsigned short bits;
                __builtin_memcpy(&bits, &hv, 2);
                H2[(w * 16 + lg * 4 + reg) * 72 + cb * 16 + lr] = bits;
            }

        const bf16x8 a3_0 = *(const bf16x8*)&H2[row * 72 + lg * 8];
        const bf16x8 a3_1 = *(const bf16x8*)&H2[row * 72 + 32 + lg * 8];
        f32x4 d3[2];
#pragma unroll
        for (int cb = 0; cb < 2; ++cb) {
            f32x4 t = __builtin_amdgcn_mfma_f32_16x16x32_bf16(a3_0, b3[cb][0], z, 0, 0, 0);
            d3[cb]  = __builtin_amdgcn_mfma_f32_16x16x32_bf16(a3_1, b3[cb][1], t, 0, 0, 0);
        }

        float* ob = out + ((size_t)p0 + w * 16) * 32;
#pragma unroll
        for (int cb = 0; cb < 2; ++cb)
#pragma unroll
            for (int reg = 0; reg < 4; ++reg)
                ob[(lg * 4 + reg) * 32 + cb * 16 + lr] = fmaxf(d3[cb][reg], 0.f);

        __syncthreads();
    }
}

// ---------------------------------------------------------------------------
// Fallback: monolithic fp32 kernel (used only if ws too small).
// ---------------------------------------------------------------------------
__global__ __launch_bounds__(256) void mono_kernel(
    const float* __restrict__ x, const float* __restrict__ table,
    const float* __restrict__ W1, const float* __restrict__ W2,
    const float* __restrict__ W3, float* __restrict__ out, EncP p)
{
    __shared__ float lds[256 * 33];
    const int tid = threadIdx.x;
    const int n = blockIdx.x * 256 + tid;
    const float x0 = x[n * 3 + 0], x1 = x[n * 3 + 1], x2 = x[n * 3 + 2];
    float xc[32];
#pragma unroll
    for (int l = 0; l < L_LEVELS; ++l) {
        const float s = p.scale[l];
        const unsigned r = p.res[l], r2 = r * r;
        float px = x0 * s + 0.5f, py = x1 * s + 0.5f, pz = x2 * s + 0.5f;
        float gx = floorf(px), gy = floorf(py), gz = floorf(pz);
        float fx = px - gx, fy = py - gy, fz = pz - gz;
        unsigned base = (unsigned)(int)gx + (unsigned)(int)gy * r + (unsigned)(int)gz * r2;
        const float* tl = table + (size_t)l * (size_t)TABLE_SIZE * 2u;
        float a0 = 0.f, a1 = 0.f;
#pragma unroll
        for (int c = 0; c < 8; ++c) {
            const unsigned dx = (c >> 2) & 1u, dy = (c >> 1) & 1u, dz = c & 1u;
            unsigned idx = (base + dx + dy * r + dz * r2) & TMASK;
            const float2 f = *(const float2*)(tl + 2u * idx);
            const float w = (dx ? fx : 1.f - fx) * (dy ? fy : 1.f - fy) * (dz ? fz : 1.f - fz);
            a0 += w * f.x; a1 += w * f.y;
        }
        xc[2 * l] = a0; xc[2 * l + 1] = a1;
    }
    float h1[64];
#pragma unroll
    for (int j = 0; j < 64; ++j) h1[j] = 0.f;
#pragma unroll
    for (int i = 0; i < 32; ++i) {
        const float v = xc[i];
#pragma unroll
        for (int j = 0; j < 64; ++j) h1[j] = fmaf(v, W1[i * 64 + j], h1[j]);
    }
#pragma unroll
    for (int j = 0; j < 64; ++j) h1[j] = fmaxf(h1[j], 0.f);
    float h2[64];
#pragma unroll
    for (int j = 0; j < 64; ++j) h2[j] = 0.f;
#pragma unroll
    for (int i = 0; i < 64; ++i) {
        const float v = h1[i];
#pragma unroll
        for (int j = 0; j < 64; ++j) h2[j] = fmaf(v, W2[i * 64 + j], h2[j]);
    }
#pragma unroll
    for (int j = 0; j < 64; ++j) h2[j] = fmaxf(h2[j], 0.f);
    float o[32];
#pragma unroll
    for (int j = 0; j < 32; ++j) o[j] = 0.f;
#pragma unroll
    for (int i = 0; i < 64; ++i) {
        const float v = h2[i];
#pragma unroll
        for (int j = 0; j < 32; ++j) o[j] = fmaf(v, W3[i * 32 + j], o[j]);
    }
#pragma unroll
    for (int j = 0; j < 32; ++j) lds[tid * 33 + j] = fmaxf(o[j], 0.f);
    __syncthreads();
    float* outb = out + (size_t)blockIdx.x * 8192;
#pragma unroll
    for (int k = 0; k < 8; ++k) {
        const int e = k * 1024 + tid * 4;
        float4 v;
        v.x = lds[((e + 0) >> 5) * 33 + ((e + 0) & 31)];
        v.y = lds[((e + 1) >> 5) * 33 + ((e + 1) & 31)];
        v.z = lds[((e + 2) >> 5) * 33 + ((e + 2) & 31)];
        v.w = lds[((e + 3) >> 5) * 33 + ((e + 3) & 31)];
        *(float4*)(outb + e) = v;
    }
}

extern "C" void kernel_launch(void* const* d_in, const int* in_sizes, int n_in,
                              void* d_out, int out_size, void* d_ws, size_t ws_size,
                              hipStream_t stream) {
    (void)in_sizes; (void)n_in; (void)out_size;

    const float* x     = (const float*)d_in[0];
    const float* table = (const float*)d_in[2];
    const float* W1    = (const float*)d_in[3];
    const float* W2    = (const float*)d_in[4];
    const float* W3    = (const float*)d_in[5];
    float* out = (float*)d_out;

    EncP p;
    const double b = exp(log(2048.0 / 16.0) / 15.0);
    for (int l = 0; l < L_LEVELS; ++l) {
        const float s = (float)(16.0 * pow(b, (double)l) - 1.0);
        p.scale[l] = s;
        p.res[l] = (unsigned)((long long)s) + 1u;
        const double r = (double)p.res[l];
        const double ws_entries = fmin(r * r * r, (double)TABLE_SIZE);
        p.fine[l] = (ws_entries * 8.0 > 262144.0) ? 1u : 0u;   // >256KB: nt
    }

    const size_t ws_needed = (size_t)L_LEVELS * N_PTS * sizeof(unsigned); // 64 MB
    if (ws_size >= ws_needed) {
        unsigned* wsu = (unsigned*)d_ws;
        hipLaunchKernelGGL(encode_kernel, dim3(65536), dim3(256), 0, stream,
                           x, table, wsu, p);
        hipLaunchKernelGGL(mlp_mfma_kernel, dim3(2048), dim3(256), 0, stream,
                           wsu, W1, W2, W3, out);
    } else {
        hipLaunchKernelGGL(mono_kernel, dim3(N_PTS / 256), dim3(256), 0, stream,
                           x, table, W1, W2, W3, out, p);
    }
}

// Round 8
// 357.423 us; speedup vs baseline: 2.6063x; 2.6063x over previous
//
#include <hip/hip_runtime.h>
#include <hip/hip_bf16.h>
#include <math.h>

constexpr int L_LEVELS = 16;
constexpr unsigned TABLE_SIZE = 1u << 19;
constexpr unsigned TMASK = TABLE_SIZE - 1u;
constexpr int N_PTS = 1048576;
constexpr size_t TBF_WORDS = (size_t)L_LEVELS * TABLE_SIZE;        // 8388608 u32
constexpr size_t XC_WORDS  = (size_t)L_LEVELS * N_PTS;             // 16777216 u32

typedef __bf16 bf16x8 __attribute__((ext_vector_type(8)));
typedef float f32x4 __attribute__((ext_vector_type(4)));

struct EncP {
    float scale[L_LEVELS];
    unsigned res[L_LEVELS];
};

struct alignas(4) u32x2 { unsigned a, b; };   // 8B load at 4B alignment (dwordx2)

__device__ __forceinline__ float bflo(unsigned u) {
    const unsigned v = u << 16;
    float f; __builtin_memcpy(&f, &v, 4); return f;
}
__device__ __forceinline__ float bfhi(unsigned u) {
    const unsigned v = u & 0xffff0000u;
    float f; __builtin_memcpy(&f, &v, 4); return f;
}

// ---------------------------------------------------------------------------
// Kernel 0: table fp32 [L][T][2] -> packed bf16 [L][T] u32 in ws.
// Halves each level's L2 slice 4MB -> 2MB (fits per-XCD L2 with headroom)
// and makes a corner-pair fetch a single 8B load.
// ---------------------------------------------------------------------------
__global__ __launch_bounds__(256) void table_bf16_kernel(
    const float* __restrict__ table, unsigned* __restrict__ tbf)
{
    const unsigned i = blockIdx.x * 256u + threadIdx.x;   // entry index < L*T
    const float2 f = *(const float2*)(table + (size_t)i * 2u);
    const __hip_bfloat162 hv = __float22bfloat162_rn(make_float2(f.x, f.y));
    unsigned u; __builtin_memcpy(&u, &hv, 4);
    tbf[i] = u;
}

// ---------------------------------------------------------------------------
// Kernel 1: grid encode, one (point, level) per thread. R5-proven structure
// (branch-per-pair, serial consumption — fastest of R4/R6/R7 variants).
// Reads packed-bf16 table: one dwordx2 per corner-pair (both dx, both feats).
// Level-phased XCD-pinned blockIdx decode (proven: FETCH 3.1GB -> 0.33GB).
// ---------------------------------------------------------------------------
__global__ __launch_bounds__(256) void encode_kernel(
    const float* __restrict__ x,
    const unsigned* __restrict__ tbf,
    unsigned* __restrict__ wsu,
    EncP p)
{
    const unsigned bid = blockIdx.x;
    const unsigned level = (bid & 7u) + 8u * (bid >> 15);
    const unsigned pblk  = (bid >> 3) & 4095u;
    const unsigned n = pblk * 256u + threadIdx.x;

    const float x0 = x[n * 3 + 0];
    const float x1 = x[n * 3 + 1];
    const float x2 = x[n * 3 + 2];

    const float s = p.scale[level];
    const unsigned r = p.res[level];
    const unsigned r2 = r * r;                   // uint32 wrap == int32 wrap bits

    float px = x0 * s + 0.5f;
    float py = x1 * s + 0.5f;
    float pz = x2 * s + 0.5f;
    float gx = floorf(px), gy = floorf(py), gz = floorf(pz);
    float fx = px - gx, fy = py - gy, fz = pz - gz;
    unsigned base = (unsigned)(int)gx + (unsigned)(int)gy * r + (unsigned)(int)gz * r2;

    const unsigned* tl = tbf + (size_t)level * TABLE_SIZE;
    const float fx1 = 1.f - fx, fy1 = 1.f - fy, fz1 = 1.f - fz;
    const float w00 = fy1 * fz1, w01 = fy1 * fz, w10 = fy * fz1, w11 = fy * fz;
    float a0 = 0.f, a1 = 0.f;

#define PAIR_C(LIN, WYZ)                                            \
    {                                                               \
        const unsigned idx0 = (LIN) & TMASK;                        \
        unsigned ua, ub;                                            \
        if (__builtin_expect(idx0 != TMASK, 1)) {                   \
            const u32x2 v = *(const u32x2*)(tl + idx0);             \
            ua = v.a; ub = v.b;                                     \
        } else {                                                    \
            ua = tl[TMASK];                                         \
            ub = tl[0];       /* python mod wrap */                 \
        }                                                           \
        const float f00 = bflo(ua), f01 = bfhi(ua);                 \
        const float f10 = bflo(ub), f11 = bfhi(ub);                 \
        const float m0 = fmaf(fx, f10, fx1 * f00);                  \
        const float m1 = fmaf(fx, f11, fx1 * f01);                  \
        a0 = fmaf((WYZ), m0, a0);                                   \
        a1 = fmaf((WYZ), m1, a1);                                   \
    }

    PAIR_C(base,           w00)   // dy=0,dz=0
    PAIR_C(base + r2,      w01)   // dy=0,dz=1
    PAIR_C(base + r,       w10)   // dy=1,dz=0
    PAIR_C(base + r + r2,  w11)   // dy=1,dz=1
#undef PAIR_C

    __hip_bfloat162 hv = __float22bfloat162_rn(make_float2(a0, a1));
    unsigned u;
    __builtin_memcpy(&u, &hv, 4);
    wsu[(size_t)level * N_PTS + n] = u;   // coalesced u32
}

// ---------------------------------------------------------------------------
// Kernel 2: MFMA MLP 32->64->64->32 (bf16 in, fp32 accum). Proven R5: ~29us.
// ---------------------------------------------------------------------------
__global__ __launch_bounds__(256) void mlp_mfma_kernel(
    const unsigned* __restrict__ wsu,
    const float* __restrict__ W1,
    const float* __restrict__ W2,
    const float* __restrict__ W3,
    float* __restrict__ out)
{
    __shared__ __align__(16) unsigned short xin[64 * 40];   // [pt][feat] pad 40
    __shared__ __align__(16) unsigned short H1[64 * 72];    // [pt][feat] pad 72
    __shared__ __align__(16) unsigned short H2[64 * 72];

    const int tid = threadIdx.x;
    const int l  = tid & 63;
    const int w  = tid >> 6;
    const int lr = l & 15;    // frag row (A) / col (B,D)
    const int lg = l >> 4;    // k-group

    bf16x8 b1[4], b2[4][2], b3[2][2];
#pragma unroll
    for (int cb = 0; cb < 4; ++cb)
#pragma unroll
        for (int e = 0; e < 8; ++e)
            b1[cb][e] = (__bf16)W1[(lg * 8 + e) * 64 + cb * 16 + lr];
#pragma unroll
    for (int cb = 0; cb < 4; ++cb)
#pragma unroll
        for (int kh = 0; kh < 2; ++kh)
#pragma unroll
            for (int e = 0; e < 8; ++e)
                b2[cb][kh][e] = (__bf16)W2[(kh * 32 + lg * 8 + e) * 64 + cb * 16 + lr];
#pragma unroll
    for (int cb = 0; cb < 2; ++cb)
#pragma unroll
        for (int kh = 0; kh < 2; ++kh)
#pragma unroll
            for (int e = 0; e < 8; ++e)
                b3[cb][kh][e] = (__bf16)W3[(kh * 32 + lg * 8 + e) * 32 + cb * 16 + lr];

    constexpr int ITERS = 8;
    const int tile0 = blockIdx.x * ITERS;
    const f32x4 z = {0.f, 0.f, 0.f, 0.f};

    for (int it = 0; it < ITERS; ++it) {
        const int p0 = (tile0 + it) * 64;

        {
            const int i  = tid & 63;
            const int lb = tid >> 6;
#pragma unroll
            for (int ps = 0; ps < 4; ++ps) {
                const int lev = ps * 4 + lb;
                const unsigned v = wsu[(size_t)lev * N_PTS + p0 + i];
                *(unsigned*)&xin[i * 40 + 2 * lev] = v;
            }
        }
        __syncthreads();

        const int row = w * 16 + lr;

        const bf16x8 a1 = *(const bf16x8*)&xin[row * 40 + lg * 8];
        f32x4 d1[4];
#pragma unroll
        for (int cb = 0; cb < 4; ++cb)
            d1[cb] = __builtin_amdgcn_mfma_f32_16x16x32_bf16(a1, b1[cb], z, 0, 0, 0);
#pragma unroll
        for (int cb = 0; cb < 4; ++cb)
#pragma unroll
            for (int reg = 0; reg < 4; ++reg) {
                const __bf16 hv = (__bf16)fmaxf(d1[cb][reg], 0.f);
                unsigned short bits;
                __builtin_memcpy(&bits, &hv, 2);
                H1[(w * 16 + lg * 4 + reg) * 72 + cb * 16 + lr] = bits;
            }

        const bf16x8 a2_0 = *(const bf16x8*)&H1[row * 72 + lg * 8];
        const bf16x8 a2_1 = *(const bf16x8*)&H1[row * 72 + 32 + lg * 8];
        f32x4 d2[4];
#pragma unroll
        for (int cb = 0; cb < 4; ++cb) {
            f32x4 t = __builtin_amdgcn_mfma_f32_16x16x32_bf16(a2_0, b2[cb][0], z, 0, 0, 0);
            d2[cb]  = __builtin_amdgcn_mfma_f32_16x16x32_bf16(a2_1, b2[cb][1], t, 0, 0, 0);
        }
#pragma unroll
        for (int cb = 0; cb < 4; ++cb)
#pragma unroll
            for (int reg = 0; reg < 4; ++reg) {
                const __bf16 hv = (__bf16)fmaxf(d2[cb][reg], 0.f);
                unsigned short bits;
                __builtin_memcpy(&bits, &hv, 2);
                H2[(w * 16 + lg * 4 + reg) * 72 + cb * 16 + lr] = bits;
            }

        const bf16x8 a3_0 = *(const bf16x8*)&H2[row * 72 + lg * 8];
        const bf16x8 a3_1 = *(const bf16x8*)&H2[row * 72 + 32 + lg * 8];
        f32x4 d3[2];
#pragma unroll
        for (int cb = 0; cb < 2; ++cb) {
            f32x4 t = __builtin_amdgcn_mfma_f32_16x16x32_bf16(a3_0, b3[cb][0], z, 0, 0, 0);
            d3[cb]  = __builtin_amdgcn_mfma_f32_16x16x32_bf16(a3_1, b3[cb][1], t, 0, 0, 0);
        }

        float* ob = out + ((size_t)p0 + w * 16) * 32;
#pragma unroll
        for (int cb = 0; cb < 2; ++cb)
#pragma unroll
            for (int reg = 0; reg < 4; ++reg)
                ob[(lg * 4 + reg) * 32 + cb * 16 + lr] = fmaxf(d3[cb][reg], 0.f);

        __syncthreads();
    }
}

// ---------------------------------------------------------------------------
// Fallback: monolithic fp32 kernel (used only if ws too small).
// ---------------------------------------------------------------------------
__global__ __launch_bounds__(256) void mono_kernel(
    const float* __restrict__ x, const float* __restrict__ table,
    const float* __restrict__ W1, const float* __restrict__ W2,
    const float* __restrict__ W3, float* __restrict__ out, EncP p)
{
    __shared__ float lds[256 * 33];
    const int tid = threadIdx.x;
    const int n = blockIdx.x * 256 + tid;
    const float x0 = x[n * 3 + 0], x1 = x[n * 3 + 1], x2 = x[n * 3 + 2];
    float xc[32];
#pragma unroll
    for (int l = 0; l < L_LEVELS; ++l) {
        const float s = p.scale[l];
        const unsigned r = p.res[l], r2 = r * r;
        float px = x0 * s + 0.5f, py = x1 * s + 0.5f, pz = x2 * s + 0.5f;
        float gx = floorf(px), gy = floorf(py), gz = floorf(pz);
        float fx = px - gx, fy = py - gy, fz = pz - gz;
        unsigned base = (unsigned)(int)gx + (unsigned)(int)gy * r + (unsigned)(int)gz * r2;
        const float* tl = table + (size_t)l * (size_t)TABLE_SIZE * 2u;
        float a0 = 0.f, a1 = 0.f;
#pragma unroll
        for (int c = 0; c < 8; ++c) {
            const unsigned dx = (c >> 2) & 1u, dy = (c >> 1) & 1u, dz = c & 1u;
            unsigned idx = (base + dx + dy * r + dz * r2) & TMASK;
            const float2 f = *(const float2*)(tl + 2u * idx);
            const float w = (dx ? fx : 1.f - fx) * (dy ? fy : 1.f - fy) * (dz ? fz : 1.f - fz);
            a0 += w * f.x; a1 += w * f.y;
        }
        xc[2 * l] = a0; xc[2 * l + 1] = a1;
    }
    float h1[64];
#pragma unroll
    for (int j = 0; j < 64; ++j) h1[j] = 0.f;
#pragma unroll
    for (int i = 0; i < 32; ++i) {
        const float v = xc[i];
#pragma unroll
        for (int j = 0; j < 64; ++j) h1[j] = fmaf(v, W1[i * 64 + j], h1[j]);
    }
#pragma unroll
    for (int j = 0; j < 64; ++j) h1[j] = fmaxf(h1[j], 0.f);
    float h2[64];
#pragma unroll
    for (int j = 0; j < 64; ++j) h2[j] = 0.f;
#pragma unroll
    for (int i = 0; i < 64; ++i) {
        const float v = h1[i];
#pragma unroll
        for (int j = 0; j < 64; ++j) h2[j] = fmaf(v, W2[i * 64 + j], h2[j]);
    }
#pragma unroll
    for (int j = 0; j < 64; ++j) h2[j] = fmaxf(h2[j], 0.f);
    float o[32];
#pragma unroll
    for (int j = 0; j < 32; ++j) o[j] = 0.f;
#pragma unroll
    for (int i = 0; i < 64; ++i) {
        const float v = h2[i];
#pragma unroll
        for (int j = 0; j < 32; ++j) o[j] = fmaf(v, W3[i * 32 + j], o[j]);
    }
#pragma unroll
    for (int j = 0; j < 32; ++j) lds[tid * 33 + j] = fmaxf(o[j], 0.f);
    __syncthreads();
    float* outb = out + (size_t)blockIdx.x * 8192;
#pragma unroll
    for (int k = 0; k < 8; ++k) {
        const int e = k * 1024 + tid * 4;
        float4 v;
        v.x = lds[((e + 0) >> 5) * 33 + ((e + 0) & 31)];
        v.y = lds[((e + 1) >> 5) * 33 + ((e + 1) & 31)];
        v.z = lds[((e + 2) >> 5) * 33 + ((e + 2) & 31)];
        v.w = lds[((e + 3) >> 5) * 33 + ((e + 3) & 31)];
        *(float4*)(outb + e) = v;
    }
}

extern "C" void kernel_launch(void* const* d_in, const int* in_sizes, int n_in,
                              void* d_out, int out_size, void* d_ws, size_t ws_size,
                              hipStream_t stream) {
    (void)in_sizes; (void)n_in; (void)out_size;

    const float* x     = (const float*)d_in[0];
    const float* table = (const float*)d_in[2];
    const float* W1    = (const float*)d_in[3];
    const float* W2    = (const float*)d_in[4];
    const float* W3    = (const float*)d_in[5];
    float* out = (float*)d_out;

    EncP p;
    const double b = exp(log(2048.0 / 16.0) / 15.0);
    for (int l = 0; l < L_LEVELS; ++l) {
        const float s = (float)(16.0 * pow(b, (double)l) - 1.0);
        p.scale[l] = s;
        p.res[l] = (unsigned)((long long)s) + 1u;
    }

    const size_t ws_needed = (TBF_WORDS + XC_WORDS) * sizeof(unsigned); // ~100.7 MB
    if (ws_size >= ws_needed) {
        unsigned* tbf = (unsigned*)d_ws;
        unsigned* xcw = tbf + TBF_WORDS;
        hipLaunchKernelGGL(table_bf16_kernel, dim3(TBF_WORDS / 256), dim3(256), 0, stream,
                           table, tbf);
        hipLaunchKernelGGL(encode_kernel, dim3(65536), dim3(256), 0, stream,
                           x, tbf, xcw, p);
        hipLaunchKernelGGL(mlp_mfma_kernel, dim3(2048), dim3(256), 0, stream,
                           xcw, W1, W2, W3, out);
    } else {
        hipLaunchKernelGGL(mono_kernel, dim3(N_PTS / 256), dim3(256), 0, stream,
                           x, table, W1, W2, W3, out, p);
    }
}

// Round 9
// 354.277 us; speedup vs baseline: 2.6295x; 1.0089x over previous
//
#include <hip/hip_runtime.h>
#include <hip/hip_bf16.h>
#include <math.h>

constexpr int L_LEVELS = 16;
constexpr unsigned TABLE_SIZE = 1u << 19;
constexpr unsigned TMASK = TABLE_SIZE - 1u;
constexpr int N_PTS = 1048576;
constexpr size_t TBF_WORDS = (size_t)L_LEVELS * TABLE_SIZE;        // 8388608 u32
constexpr size_t XC_WORDS  = (size_t)L_LEVELS * N_PTS;             // 16777216 u32

typedef __bf16 bf16x8 __attribute__((ext_vector_type(8)));
typedef float f32x4 __attribute__((ext_vector_type(4)));

struct EncP {
    float scale[L_LEVELS];
    unsigned res[L_LEVELS];
    // XCD-balanced schedule: per XCD, up to 6 (level, pblk_base, count) segs
    unsigned seglev[8][6];
    unsigned segbase[8][6];
    unsigned segcnt[8][6];
};

struct alignas(4) u32x2 { unsigned a, b; };   // 8B load at 4B alignment (dwordx2)

__device__ __forceinline__ float bflo(unsigned u) {
    const unsigned v = u << 16;
    float f; __builtin_memcpy(&f, &v, 4); return f;
}
__device__ __forceinline__ float bfhi(unsigned u) {
    const unsigned v = u & 0xffff0000u;
    float f; __builtin_memcpy(&f, &v, 4); return f;
}

// ---------------------------------------------------------------------------
// Kernel 0: table fp32 [L][T][2] -> packed bf16 [L][T] u32 in ws.
// 2 entries/thread: float4 read, uint2 write (pure streaming).
// ---------------------------------------------------------------------------
__global__ __launch_bounds__(256) void table_bf16_kernel(
    const float* __restrict__ table, unsigned* __restrict__ tbf)
{
    const size_t i = (size_t)blockIdx.x * 256u + threadIdx.x;   // pair index
    const float4 f = *(const float4*)(table + i * 4u);
    __hip_bfloat162 h0 = __float22bfloat162_rn(make_float2(f.x, f.y));
    __hip_bfloat162 h1 = __float22bfloat162_rn(make_float2(f.z, f.w));
    unsigned u0, u1;
    __builtin_memcpy(&u0, &h0, 4);
    __builtin_memcpy(&u1, &h1, 4);
    uint2 uu; uu.x = u0; uu.y = u1;
    *(uint2*)(tbf + i * 2u) = uu;
}

// ---------------------------------------------------------------------------
// Kernel 1: grid encode, one (point, level) per thread. R8-proven inner loop
// (branch-per-pair serial consumption, packed-bf16 dwordx2 gathers).
// NEW: XCD-balanced level schedule via kernarg segment LUT —
//   cheap levels 0-3 striped across all XCDs, full levels 4-15 split as
//   1.5-level contiguous chunks (<=2 slices per XCD, visited sequentially).
// ---------------------------------------------------------------------------
__global__ __launch_bounds__(256) void encode_kernel(
    const float* __restrict__ x,
    const unsigned* __restrict__ tbf,
    unsigned* __restrict__ wsu,
    EncP p)
{
    const unsigned bid = blockIdx.x;
    const unsigned xcd = bid & 7u;      // round-robin dispatch heuristic (proven R3+)
    unsigned seq = bid >> 3;            // 0..8191 per XCD

    unsigned level = 0, pblk = 0;
#pragma unroll
    for (int i = 0; i < 6; ++i) {
        const unsigned c = p.segcnt[xcd][i];
        if (seq < c) { level = p.seglev[xcd][i]; pblk = p.segbase[xcd][i] + seq; break; }
        seq -= c;
    }

    const unsigned n = pblk * 256u + threadIdx.x;

    const float x0 = x[n * 3 + 0];
    const float x1 = x[n * 3 + 1];
    const float x2 = x[n * 3 + 2];

    const float s = p.scale[level];
    const unsigned r = p.res[level];
    const unsigned r2 = r * r;                   // uint32 wrap == int32 wrap bits

    float px = x0 * s + 0.5f;
    float py = x1 * s + 0.5f;
    float pz = x2 * s + 0.5f;
    float gx = floorf(px), gy = floorf(py), gz = floorf(pz);
    float fx = px - gx, fy = py - gy, fz = pz - gz;
    unsigned base = (unsigned)(int)gx + (unsigned)(int)gy * r + (unsigned)(int)gz * r2;

    const unsigned* tl = tbf + (size_t)level * TABLE_SIZE;
    const float fx1 = 1.f - fx, fy1 = 1.f - fy, fz1 = 1.f - fz;
    const float w00 = fy1 * fz1, w01 = fy1 * fz, w10 = fy * fz1, w11 = fy * fz;
    float a0 = 0.f, a1 = 0.f;

#define PAIR_C(LIN, WYZ)                                            \
    {                                                               \
        const unsigned idx0 = (LIN) & TMASK;                        \
        unsigned ua, ub;                                            \
        if (__builtin_expect(idx0 != TMASK, 1)) {                   \
            const u32x2 v = *(const u32x2*)(tl + idx0);             \
            ua = v.a; ub = v.b;                                     \
        } else {                                                    \
            ua = tl[TMASK];                                         \
            ub = tl[0];       /* python mod wrap */                 \
        }                                                           \
        const float f00 = bflo(ua), f01 = bfhi(ua);                 \
        const float f10 = bflo(ub), f11 = bfhi(ub);                 \
        const float m0 = fmaf(fx, f10, fx1 * f00);                  \
        const float m1 = fmaf(fx, f11, fx1 * f01);                  \
        a0 = fmaf((WYZ), m0, a0);                                   \
        a1 = fmaf((WYZ), m1, a1);                                   \
    }

    PAIR_C(base,           w00)   // dy=0,dz=0
    PAIR_C(base + r2,      w01)   // dy=0,dz=1
    PAIR_C(base + r,       w10)   // dy=1,dz=0
    PAIR_C(base + r + r2,  w11)   // dy=1,dz=1
#undef PAIR_C

    __hip_bfloat162 hv = __float22bfloat162_rn(make_float2(a0, a1));
    unsigned u;
    __builtin_memcpy(&u, &hv, 4);
    wsu[(size_t)level * N_PTS + n] = u;   // coalesced u32
}

// ---------------------------------------------------------------------------
// Kernel 2: MFMA MLP 32->64->64->32 (bf16 in, fp32 accum). Proven R5: ~29us.
// ---------------------------------------------------------------------------
__global__ __launch_bounds__(256) void mlp_mfma_kernel(
    const unsigned* __restrict__ wsu,
    const float* __restrict__ W1,
    const float* __restrict__ W2,
    const float* __restrict__ W3,
    float* __restrict__ out)
{
    __shared__ __align__(16) unsigned short xin[64 * 40];   // [pt][feat] pad 40
    __shared__ __align__(16) unsigned short H1[64 * 72];    // [pt][feat] pad 72
    __shared__ __align__(16) unsigned short H2[64 * 72];

    const int tid = threadIdx.x;
    const int l  = tid & 63;
    const int w  = tid >> 6;
    const int lr = l & 15;    // frag row (A) / col (B,D)
    const int lg = l >> 4;    // k-group

    bf16x8 b1[4], b2[4][2], b3[2][2];
#pragma unroll
    for (int cb = 0; cb < 4; ++cb)
#pragma unroll
        for (int e = 0; e < 8; ++e)
            b1[cb][e] = (__bf16)W1[(lg * 8 + e) * 64 + cb * 16 + lr];
#pragma unroll
    for (int cb = 0; cb < 4; ++cb)
#pragma unroll
        for (int kh = 0; kh < 2; ++kh)
#pragma unroll
            for (int e = 0; e < 8; ++e)
                b2[cb][kh][e] = (__bf16)W2[(kh * 32 + lg * 8 + e) * 64 + cb * 16 + lr];
#pragma unroll
    for (int cb = 0; cb < 2; ++cb)
#pragma unroll
        for (int kh = 0; kh < 2; ++kh)
#pragma unroll
            for (int e = 0; e < 8; ++e)
                b3[cb][kh][e] = (__bf16)W3[(kh * 32 + lg * 8 + e) * 32 + cb * 16 + lr];

    constexpr int ITERS = 8;
    const int tile0 = blockIdx.x * ITERS;
    const f32x4 z = {0.f, 0.f, 0.f, 0.f};

    for (int it = 0; it < ITERS; ++it) {
        const int p0 = (tile0 + it) * 64;

        {
            const int i  = tid & 63;
            const int lb = tid >> 6;
#pragma unroll
            for (int ps = 0; ps < 4; ++ps) {
                const int lev = ps * 4 + lb;
                const unsigned v = wsu[(size_t)lev * N_PTS + p0 + i];
                *(unsigned*)&xin[i * 40 + 2 * lev] = v;
            }
        }
        __syncthreads();

        const int row = w * 16 + lr;

        const bf16x8 a1 = *(const bf16x8*)&xin[row * 40 + lg * 8];
        f32x4 d1[4];
#pragma unroll
        for (int cb = 0; cb < 4; ++cb)
            d1[cb] = __builtin_amdgcn_mfma_f32_16x16x32_bf16(a1, b1[cb], z, 0, 0, 0);
#pragma unroll
        for (int cb = 0; cb < 4; ++cb)
#pragma unroll
            for (int reg = 0; reg < 4; ++reg) {
                const __bf16 hv = (__bf16)fmaxf(d1[cb][reg], 0.f);
                unsigned short bits;
                __builtin_memcpy(&bits, &hv, 2);
                H1[(w * 16 + lg * 4 + reg) * 72 + cb * 16 + lr] = bits;
            }

        const bf16x8 a2_0 = *(const bf16x8*)&H1[row * 72 + lg * 8];
        const bf16x8 a2_1 = *(const bf16x8*)&H1[row * 72 + 32 + lg * 8];
        f32x4 d2[4];
#pragma unroll
        for (int cb = 0; cb < 4; ++cb) {
            f32x4 t = __builtin_amdgcn_mfma_f32_16x16x32_bf16(a2_0, b2[cb][0], z, 0, 0, 0);
            d2[cb]  = __builtin_amdgcn_mfma_f32_16x16x32_bf16(a2_1, b2[cb][1], t, 0, 0, 0);
        }
#pragma unroll
        for (int cb = 0; cb < 4; ++cb)
#pragma unroll
            for (int reg = 0; reg < 4; ++reg) {
                const __bf16 hv = (__bf16)fmaxf(d2[cb][reg], 0.f);
                unsigned short bits;
                __builtin_memcpy(&bits, &hv, 2);
                H2[(w * 16 + lg * 4 + reg) * 72 + cb * 16 + lr] = bits;
            }

        const bf16x8 a3_0 = *(const bf16x8*)&H2[row * 72 + lg * 8];
        const bf16x8 a3_1 = *(const bf16x8*)&H2[row * 72 + 32 + lg * 8];
        f32x4 d3[2];
#pragma unroll
        for (int cb = 0; cb < 2; ++cb) {
            f32x4 t = __builtin_amdgcn_mfma_f32_16x16x32_bf16(a3_0, b3[cb][0], z, 0, 0, 0);
            d3[cb]  = __builtin_amdgcn_mfma_f32_16x16x32_bf16(a3_1, b3[cb][1], t, 0, 0, 0);
        }

        float* ob = out + ((size_t)p0 + w * 16) * 32;
#pragma unroll
        for (int cb = 0; cb < 2; ++cb)
#pragma unroll
            for (int reg = 0; reg < 4; ++reg)
                ob[(lg * 4 + reg) * 32 + cb * 16 + lr] = fmaxf(d3[cb][reg], 0.f);

        __syncthreads();
    }
}

// ---------------------------------------------------------------------------
// Fallback: monolithic fp32 kernel (used only if ws too small).
// ---------------------------------------------------------------------------
__global__ __launch_bounds__(256) void mono_kernel(
    const float* __restrict__ x, const float* __restrict__ table,
    const float* __restrict__ W1, const float* __restrict__ W2,
    const float* __restrict__ W3, float* __restrict__ out, EncP p)
{
    __shared__ float lds[256 * 33];
    const int tid = threadIdx.x;
    const int n = blockIdx.x * 256 + tid;
    const float x0 = x[n * 3 + 0], x1 = x[n * 3 + 1], x2 = x[n * 3 + 2];
    float xc[32];
#pragma unroll
    for (int l = 0; l < L_LEVELS; ++l) {
        const float s = p.scale[l];
        const unsigned r = p.res[l], r2 = r * r;
        float px = x0 * s + 0.5f, py = x1 * s + 0.5f, pz = x2 * s + 0.5f;
        float gx = floorf(px), gy = floorf(py), gz = floorf(pz);
        float fx = px - gx, fy = py - gy, fz = pz - gz;
        unsigned base = (unsigned)(int)gx + (unsigned)(int)gy * r + (unsigned)(int)gz * r2;
        const float* tl = table + (size_t)l * (size_t)TABLE_SIZE * 2u;
        float a0 = 0.f, a1 = 0.f;
#pragma unroll
        for (int c = 0; c < 8; ++c) {
            const unsigned dx = (c >> 2) & 1u, dy = (c >> 1) & 1u, dz = c & 1u;
            unsigned idx = (base + dx + dy * r + dz * r2) & TMASK;
            const float2 f = *(const float2*)(tl + 2u * idx);
            const float w = (dx ? fx : 1.f - fx) * (dy ? fy : 1.f - fy) * (dz ? fz : 1.f - fz);
            a0 += w * f.x; a1 += w * f.y;
        }
        xc[2 * l] = a0; xc[2 * l + 1] = a1;
    }
    float h1[64];
#pragma unroll
    for (int j = 0; j < 64; ++j) h1[j] = 0.f;
#pragma unroll
    for (int i = 0; i < 32; ++i) {
        const float v = xc[i];
#pragma unroll
        for (int j = 0; j < 64; ++j) h1[j] = fmaf(v, W1[i * 64 + j], h1[j]);
    }
#pragma unroll
    for (int j = 0; j < 64; ++j) h1[j] = fmaxf(h1[j], 0.f);
    float h2[64];
#pragma unroll
    for (int j = 0; j < 64; ++j) h2[j] = 0.f;
#pragma unroll
    for (int i = 0; i < 64; ++i) {
        const float v = h1[i];
#pragma unroll
        for (int j = 0; j < 64; ++j) h2[j] = fmaf(v, W2[i * 64 + j], h2[j]);
    }
#pragma unroll
    for (int j = 0; j < 64; ++j) h2[j] = fmaxf(h2[j], 0.f);
    float o[32];
#pragma unroll
    for (int j = 0; j < 32; ++j) o[j] = 0.f;
#pragma unroll
    for (int i = 0; i < 64; ++i) {
        const float v = h2[i];
#pragma unroll
        for (int j = 0; j < 32; ++j) o[j] = fmaf(v, W3[i * 32 + j], o[j]);
    }
#pragma unroll
    for (int j = 0; j < 32; ++j) lds[tid * 33 + j] = fmaxf(o[j], 0.f);
    __syncthreads();
    float* outb = out + (size_t)blockIdx.x * 8192;
#pragma unroll
    for (int k = 0; k < 8; ++k) {
        const int e = k * 1024 + tid * 4;
        float4 v;
        v.x = lds[((e + 0) >> 5) * 33 + ((e + 0) & 31)];
        v.y = lds[((e + 1) >> 5) * 33 + ((e + 1) & 31)];
        v.z = lds[((e + 2) >> 5) * 33 + ((e + 2) & 31)];
        v.w = lds[((e + 3) >> 5) * 33 + ((e + 3) & 31)];
        *(float4*)(outb + e) = v;
    }
}

extern "C" void kernel_launch(void* const* d_in, const int* in_sizes, int n_in,
                              void* d_out, int out_size, void* d_ws, size_t ws_size,
                              hipStream_t stream) {
    (void)in_sizes; (void)n_in; (void)out_size;

    const float* x     = (const float*)d_in[0];
    const float* table = (const float*)d_in[2];
    const float* W1    = (const float*)d_in[3];
    const float* W2    = (const float*)d_in[4];
    const float* W3    = (const float*)d_in[5];
    float* out = (float*)d_out;

    EncP p;
    const double b = exp(log(2048.0 / 16.0) / 15.0);
    for (int l = 0; l < L_LEVELS; ++l) {
        const float s = (float)(16.0 * pow(b, (double)l) - 1.0);
        p.scale[l] = s;
        p.res[l] = (unsigned)((long long)s) + 1u;
    }

    // XCD-balanced schedule. Full levels 4..15 (L2-bound, ~equal cost/block):
    // each XCD takes a contiguous 6144-block chunk of the 49152-block
    // concatenation -> 1.5 levels, <=2 slices, visited sequentially.
    // Cheap levels 0..3 (<=290KB slices): striped 2048 blocks per XCD.
    for (int k = 0; k < 8; ++k) {
        int ns = 0;
        unsigned c0 = 6144u * k, c1 = 6144u * (k + 1);
        while (c0 < c1) {
            unsigned lev = 4u + c0 / 4096u;
            unsigned upto = ((c0 / 4096u) + 1u) * 4096u; if (upto > c1) upto = c1;
            p.seglev[k][ns] = lev; p.segbase[k][ns] = c0 % 4096u; p.segcnt[k][ns] = upto - c0;
            c0 = upto; ++ns;
        }
        c0 = 2048u * k; c1 = 2048u * (k + 1);
        while (c0 < c1) {
            unsigned lev = c0 / 4096u;
            unsigned upto = ((c0 / 4096u) + 1u) * 4096u; if (upto > c1) upto = c1;
            p.seglev[k][ns] = lev; p.segbase[k][ns] = c0 % 4096u; p.segcnt[k][ns] = upto - c0;
            c0 = upto; ++ns;
        }
        for (; ns < 6; ++ns) { p.seglev[k][ns] = 0; p.segbase[k][ns] = 0; p.segcnt[k][ns] = 0; }
    }

    const size_t ws_needed = (TBF_WORDS + XC_WORDS) * sizeof(unsigned); // ~100.7 MB
    if (ws_size >= ws_needed) {
        unsigned* tbf = (unsigned*)d_ws;
        unsigned* xcw = tbf + TBF_WORDS;
        hipLaunchKernelGGL(table_bf16_kernel, dim3(TBF_WORDS / 512), dim3(256), 0, stream,
                           table, tbf);
        hipLaunchKernelGGL(encode_kernel, dim3(65536), dim3(256), 0, stream,
                           x, tbf, xcw, p);
        hipLaunchKernelGGL(mlp_mfma_kernel, dim3(2048), dim3(256), 0, stream,
                           xcw, W1, W2, W3, out);
    } else {
        hipLaunchKernelGGL(mono_kernel, dim3(N_PTS / 256), dim3(256), 0, stream,
                           x, table, W1, W2, W3, out, p);
    }
}